// Round 4
// baseline (366.229 us; speedup 1.0000x reference)
//
#include <hip/hip_runtime.h>

// ---------------- problem constants ----------------
constexpr int CB   = 4;
constexpr int CS   = 1024;
constexpr int CD   = 1024;
constexpr int CH   = 16;
constexpr int CDFF = 4096;
constexpr int CNT  = CB * CS;   // 4096 tokens
constexpr size_t SZE = (size_t)CNT * CD;   // partial-slice stride (elems)

typedef unsigned short ush;
typedef __bf16 bf16_t;
typedef bf16_t bf16x8 __attribute__((ext_vector_type(8)));
typedef float  f32x4  __attribute__((ext_vector_type(4)));

__device__ __forceinline__ ush f2bf(float f) {
    union { float f; unsigned u; } v; v.f = f;
    unsigned u = v.u;
    return (ush)((u + 0x7fffu + ((u >> 16) & 1u)) >> 16);
}
__device__ __forceinline__ float bf2f(ush h) {
    union { unsigned u; float f; } v; v.u = ((unsigned)h) << 16;
    return v.f;
}
__device__ __forceinline__ void ub8(uint4 v, float* d) {
    d[0] = bf2f((ush)v.x); d[1] = bf2f((ush)(v.x >> 16));
    d[2] = bf2f((ush)v.y); d[3] = bf2f((ush)(v.y >> 16));
    d[4] = bf2f((ush)v.z); d[5] = bf2f((ush)(v.z >> 16));
    d[6] = bf2f((ush)v.w); d[7] = bf2f((ush)(v.w >> 16));
}
__device__ __forceinline__ uint4 pb8(const float* d) {
    uint4 v;
    v.x = (unsigned)f2bf(d[0]) | ((unsigned)f2bf(d[1]) << 16);
    v.y = (unsigned)f2bf(d[2]) | ((unsigned)f2bf(d[3]) << 16);
    v.z = (unsigned)f2bf(d[4]) | ((unsigned)f2bf(d[5]) << 16);
    v.w = (unsigned)f2bf(d[6]) | ((unsigned)f2bf(d[7]) << 16);
    return v;
}

// async global->LDS, 16B per lane (dest = wave-uniform base + lane*16)
__device__ __forceinline__ void gll16(const void* g, void* l) {
    __builtin_amdgcn_global_load_lds((const __attribute__((address_space(1))) void*)g,
                                     (__attribute__((address_space(3))) void*)l,
                                     16, 0, 0);
}

// ---------------- fused conversions (x + all weights) + wcol zero ----------------
constexpr int Q4 = (CD * CD) / 4;
__global__ __launch_bounds__(256) void k_convert_all(
        const float4* __restrict__ Wq, const float4* __restrict__ Wk,
        const float4* __restrict__ Wv, const float4* __restrict__ Ws,
        const float4* __restrict__ Wo, const float4* __restrict__ Wh,
        const float4* __restrict__ Wp1, const float4* __restrict__ Wp2,
        const float4* __restrict__ x, uint4* __restrict__ arena,
        uint4* __restrict__ xb, float4* __restrict__ wz) {
    int i = blockIdx.x * 256 + threadIdx.x;
    int stride = gridDim.x * 256;
    for (int i2 = i; i2 < (CB * CH * CS) / 4; i2 += stride)
        wz[i2] = (float4){0.f, 0.f, 0.f, 0.f};
    for (; i < 9 * Q4; i += stride) {
        const int F = i * 2;
        const int seg = F >> 18;
        const float4* src; int off;
        if (seg < 6) {
            src = (seg == 0) ? Wq : (seg == 1) ? Wk : (seg == 2) ? Wv
                : (seg == 3) ? Ws : (seg == 4) ? Wo : Wh;
            off = F & (Q4 - 1);
        } else if (seg < 10) { src = Wp1; off = F - 6 * Q4; }
        else if (seg < 14)   { src = Wp2; off = F - 10 * Q4; }
        else                 { src = x;   off = F - 14 * Q4; }
        float4 a = src[off], b = src[off + 1];
        uint4 o;
        o.x = (unsigned)f2bf(a.x) | ((unsigned)f2bf(a.y) << 16);
        o.y = (unsigned)f2bf(a.z) | ((unsigned)f2bf(a.w) << 16);
        o.z = (unsigned)f2bf(b.x) | ((unsigned)f2bf(b.y) << 16);
        o.w = (unsigned)f2bf(b.z) | ((unsigned)f2bf(b.w) << 16);
        if (seg < 14) arena[i] = o;
        else          xb[i - 7 * Q4] = o;
    }
}

// ======== 8-phase 256x256 bf16 MFMA GEMM (m201-style), C = A[M,K]*B[N,K]^T ========
// 512 thr = 8 waves (2M x 4N), per-wave 128x64 output (acc[8][4]). BK=64.
// LDS: 2 slots x (A 256x64 | B 256x64) = 128 KB; halves A0,A1,B0,B1 per slot.
// Iter computes tiles (t,t+1); quadrant order (A0B0),(A0B1),(A1B1),(A1B0).
// Stage stream (1 half-tile = 2 gll16 per phase):
//   ph1:A1(t+1) ph2:B0(t+1) ph3:A0(t+2) ph4:B1(t+2) ph5:A1(t+2) ph6:B0(t+2)
//   ph7:A0(t+3) ph8:B1(t+3)     (wrap: A1/B0 of odd tiles staged next iter ph1/2)
// Counted checkpoints at ph4/ph8: vmcnt(4) allows only the 2 newest half-tiles
// outstanding -> everything the next 4 phases read is resident. Never vmcnt(0)
// mid-steady-state. EPI 0: bf16 partials (split-K, slices 0,1->Cb, 2,3->out2).
// EPI 3: +bias relu. EPI 4: QKVS per-head LN (q,k,v) + raw s.
template <int EPI, int SPLITK>
__global__ __launch_bounds__(512, 2) void k_gemm8(
        const ush* __restrict__ A, const ush* __restrict__ Bm,
        ush* __restrict__ Cb,
        const float* __restrict__ bias, const float* __restrict__ bias2,
        ush* __restrict__ out2, ush* __restrict__ out3, ush* __restrict__ sb,
        int N, int K) {
    __shared__ ush sm[2 * 32768];          // 128 KB

    const int tid  = threadIdx.x;
    const int wave = tid >> 6, lane = tid & 63;
    const int quad = lane >> 4, r = lane & 15;
    const int wm = wave >> 2, wn = wave & 3;   // 2M x 4N -> wave tile 128x64
    const int bm = blockIdx.x, bn = blockIdx.y;
    const int kcnt = K / SPLITK, kbase = blockIdx.z * kcnt;
    const int NT = kcnt >> 6;                  // must be even (16 here)

    ush* dst0 = Cb;
    if (SPLITK > 1)
        dst0 = ((blockIdx.z < 2) ? Cb : out2)
             + (size_t)(blockIdx.z & 1) * (size_t)gridDim.x * 256 * N;

    // staging: XOR-swizzled global source, linear LDS dest
    const int trow = tid >> 3, tk8 = tid & 7;
    const int kcl  = tk8 ^ (trow & 7);
    const ush* ap = A  + (size_t)(bm * 256 + trow) * K + kbase + kcl * 8;
    const ush* bp = Bm + (size_t)(bn * 256 + trow) * K + kbase + kcl * 8;

    f32x4 acc[8][4];
#pragma unroll
    for (int i = 0; i < 8; i++)
#pragma unroll
        for (int j = 0; j < 4; j++) acc[i][j] = (f32x4){0.f, 0.f, 0.f, 0.f};

    // stage one half-tile: mat 0=A 1=B, half hf, tile tt -> slot tt&1
    auto SH = [&](int mat, int hf, int tt) {
        const ush* src = (mat ? bp : ap) + tt * 64 + (size_t)(hf * 128) * K;
        ush* d = sm + (tt & 1) * 32768 + mat * 16384 + hf * 8192 + tid * 8;
        gll16(src,                  d);
        gll16(src + (size_t)64 * K, d + 4096);
    };

    // prologue: tile0 full + tile1 {A0,B1}; allow tile1's 4 loads outstanding
    SH(0, 0, 0); SH(0, 1, 0); SH(1, 0, 0); SH(1, 1, 0);
    SH(0, 0, 1); SH(1, 1, 1);
    asm volatile("s_waitcnt vmcnt(4)" ::: "memory");
    __builtin_amdgcn_s_barrier();

    const ush* s1b = sm + 32768;
    for (int t = 0; t < NT; t += 2) {
        const bool s2 = (t + 2) < NT, s3 = (t + 3) < NT;
        bf16x8 a[4][2], b0r[2][2], b1r[2][2];

        // lambdas for register subtile reads (slot base sl)
        auto RA = [&](int ah, const ush* sl) {
#pragma unroll
            for (int i = 0; i < 4; i++)
#pragma unroll
                for (int h = 0; h < 2; h++) {
                    const int row = wm * 128 + ah * 64 + i * 16 + r;
                    a[i][h] = *(const bf16x8*)(sl + row * 64 + ((((h << 2) | quad) ^ (row & 7)) << 3));
                }
        };
        auto RB = [&](bf16x8 (&bq)[2][2], int bh, const ush* sl) {
#pragma unroll
            for (int j = 0; j < 2; j++)
#pragma unroll
                for (int h = 0; h < 2; h++) {
                    const int row = wn * 64 + bh * 32 + j * 16 + r;
                    bq[j][h] = *(const bf16x8*)(sl + 16384 + row * 64 + ((((h << 2) | quad) ^ (row & 7)) << 3));
                }
        };
        auto MM = [&](bf16x8 (&bq)[2][2], int ai, int bj) {
            __builtin_amdgcn_s_setprio(1);
#pragma unroll
            for (int i = 0; i < 4; i++)
#pragma unroll
                for (int j = 0; j < 2; j++)
#pragma unroll
                    for (int h = 0; h < 2; h++)
                        acc[ai + i][bj + j] =
                            __builtin_amdgcn_mfma_f32_16x16x32_bf16(a[i][h], bq[j][h], acc[ai + i][bj + j], 0, 0, 0);
            __builtin_amdgcn_s_setprio(0);
        };
#define PH_SYNC  __builtin_amdgcn_s_barrier();                         \
                 asm volatile("s_waitcnt lgkmcnt(0)" ::: "memory");    \
                 __builtin_amdgcn_sched_barrier(0);

        // ---- tile t (slot 0) ----
        RA(0, sm); RB(b0r, 0, sm);  SH(0, 1, t + 1);            // ph1: q(A0,B0)
        PH_SYNC; MM(b0r, 0, 0); __builtin_amdgcn_s_barrier();
        RB(b1r, 1, sm);             SH(1, 0, t + 1);            // ph2: q(A0,B1)
        PH_SYNC; MM(b1r, 0, 2); __builtin_amdgcn_s_barrier();
        RA(1, sm);                  if (s2) SH(0, 0, t + 2);    // ph3: q(A1,B1)
        PH_SYNC; MM(b1r, 4, 2); __builtin_amdgcn_s_barrier();
        if (s2) SH(1, 1, t + 2);                                 // ph4: q(A1,B0)
        MM(b0r, 4, 0);
        if (s2) asm volatile("s_waitcnt vmcnt(4)" ::: "memory");
        else    asm volatile("s_waitcnt vmcnt(0)" ::: "memory");
        __builtin_amdgcn_s_barrier();

        // ---- tile t+1 (slot 1) ----
        RA(0, s1b); RB(b0r, 0, s1b); if (s2) SH(0, 1, t + 2);   // ph5
        PH_SYNC; MM(b0r, 0, 0); __builtin_amdgcn_s_barrier();
        RB(b1r, 1, s1b);             if (s2) SH(1, 0, t + 2);   // ph6
        PH_SYNC; MM(b1r, 0, 2); __builtin_amdgcn_s_barrier();
        RA(1, s1b);                  if (s3) SH(0, 0, t + 3);   // ph7
        PH_SYNC; MM(b1r, 4, 2); __builtin_amdgcn_s_barrier();
        if (s3) SH(1, 1, t + 3);                                 // ph8
        MM(b0r, 4, 0);
        if (s3) asm volatile("s_waitcnt vmcnt(4)" ::: "memory");
        else    asm volatile("s_waitcnt vmcnt(0)" ::: "memory");
        __builtin_amdgcn_s_barrier();
#undef PH_SYNC
    }
    asm volatile("s_waitcnt vmcnt(0)" ::: "memory");
    __syncthreads();

    // ---- epilogue: two 128-row halves through LDS ----
    constexpr int EPS2 = 264;
    ush* Cs = sm;
#pragma unroll
    for (int hh = 0; hh < 2; hh++) {
        if (wm == hh) {
            if (EPI == 4 && bn < 12) {
                float g4[4], b4[4];
#pragma unroll
                for (int j = 0; j < 4; j++) { g4[j] = bias[j * 16 + r]; b4[j] = bias2[j * 16 + r]; }
#pragma unroll
                for (int i = 0; i < 8; i++) {
                    const int row = i * 16 + quad * 4;
#pragma unroll
                    for (int g = 0; g < 4; g++) {
                        float s = 0.f, q = 0.f;
#pragma unroll
                        for (int j = 0; j < 4; j++) { float v = acc[i][j][g]; s += v; q += v * v; }
                        s += __shfl_xor(s, 1); q += __shfl_xor(q, 1);
                        s += __shfl_xor(s, 2); q += __shfl_xor(q, 2);
                        s += __shfl_xor(s, 4); q += __shfl_xor(q, 4);
                        s += __shfl_xor(s, 8); q += __shfl_xor(q, 8);
                        float mu   = s * (1.f / 64.f);
                        float rstd = rsqrtf(q * (1.f / 64.f) - mu * mu + 1e-5f);
#pragma unroll
                        for (int j = 0; j < 4; j++) {
                            float y = (acc[i][j][g] - mu) * rstd * g4[j] + b4[j];
                            Cs[(row + g) * EPS2 + wn * 64 + j * 16 + r] = f2bf(y);
                        }
                    }
                }
            } else {
#pragma unroll
                for (int i = 0; i < 8; i++) {
#pragma unroll
                    for (int j = 0; j < 4; j++) {
                        const int col = wn * 64 + j * 16 + r;
                        float bv = (EPI == 3) ? bias[bn * 256 + col] : 0.f;
#pragma unroll
                        for (int g = 0; g < 4; g++) {
                            float v = acc[i][j][g] + bv;
                            if (EPI == 3) v = fmaxf(v, 0.f);
                            Cs[(i * 16 + quad * 4 + g) * EPS2 + col] = f2bf(v);
                        }
                    }
                }
            }
        }
        __syncthreads();
        ush* dst = dst0; int colbase = bn * 256, Nn = N;
        if (EPI == 4) {
            Nn = 1024;
            const int quarter = bn >> 2;
            colbase = (bn & 3) * 256;
            dst = (quarter == 0) ? Cb : (quarter == 1) ? out2 : (quarter == 2) ? out3 : sb;
        }
#pragma unroll
        for (int p2 = 0; p2 < 8; p2++) {
            const int rr = p2 * 16 + (tid >> 5);
            const int cc = (tid & 31) * 8;
            uint4 vv = *(const uint4*)&Cs[rr * EPS2 + cc];
            *(uint4*)&dst[(size_t)(bm * 256 + hh * 128 + rr) * Nn + colbase + cc] = vv;
        }
        __syncthreads();
    }
}

// ---------------- r0-proven 128-row GEMM (kept for Wo / Wh, TN=64) ----------------
template <int TN, int EPI, int SPLITK>
__global__ __launch_bounds__(256, 4) void k_gemm_bt(
        const ush* __restrict__ A, const ush* __restrict__ Bm,
        ush* __restrict__ Cb,
        const float* __restrict__ bias, const float* __restrict__ bias2,
        ush* __restrict__ out2, ush* __restrict__ out3, ush* __restrict__ sb,
        int N, int K) {
    constexpr int NJ  = TN / 32;
    constexpr int BCH = TN / 32;
    constexpr int EPS = TN + 8;
    constexpr int STG = (128 + TN) * 64;
    constexpr int LDS_USH = (STG > 128 * EPS) ? STG : 128 * EPS;
    __shared__ ush smem[LDS_USH];
    ush* As = smem;
    ush* Bs = smem + 128 * 64;
    ush* Cs = smem;

    const int tid  = threadIdx.x;
    const int wave = tid >> 6, lane = tid & 63;
    const int quad = lane >> 4, r = lane & 15;
    const int wm = wave >> 1, wn = wave & 1;
    const int bm = blockIdx.x, bn = blockIdx.y;

    const int kcnt  = K / SPLITK;
    const int kbase = blockIdx.z * kcnt;
    ush* dst0 = Cb;
    if (SPLITK > 1) dst0 += (size_t)blockIdx.z * (size_t)gridDim.x * 128 * N;

    const int trow = tid >> 3, tk8 = tid & 7;
    const int kcl  = tk8 ^ (trow & 7);
    const ush* ap = A  + (size_t)(bm * 128 + trow) * K + kbase + kcl * 8;
    const ush* bp = Bm + (size_t)(bn * TN  + trow) * K + kbase + kcl * 8;
    ush* asd = As + tid * 8;
    ush* bsd = Bs + tid * 8;
    const size_t cstep = (size_t)32 * K;

    f32x4 acc[4][NJ];
#pragma unroll
    for (int i = 0; i < 4; i++)
#pragma unroll
        for (int j = 0; j < NJ; j++) acc[i][j] = (f32x4){0.f, 0.f, 0.f, 0.f};

    const int rx = r & 7;
    for (int k0 = 0; k0 < kcnt; k0 += 64) {
#pragma unroll
        for (int c = 0; c < 4; c++)   gll16(ap + c * cstep, asd + c * 2048);
#pragma unroll
        for (int c = 0; c < BCH; c++) gll16(bp + c * cstep, bsd + c * 2048);
        ap += 64; bp += 64;
        __syncthreads();
#pragma unroll
        for (int h = 0; h < 2; h++) {
            const int kx = (((h << 2) | quad) ^ rx) * 8;
            bf16x8 af[4], bfv[NJ];
#pragma unroll
            for (int i = 0; i < 4; i++)
                af[i] = *(const bf16x8*)(As + (wm * 64 + i * 16 + r) * 64 + kx);
#pragma unroll
            for (int j = 0; j < NJ; j++)
                bfv[j] = *(const bf16x8*)(Bs + (wn * (TN / 2) + j * 16 + r) * 64 + kx);
#pragma unroll
            for (int i = 0; i < 4; i++)
#pragma unroll
                for (int j = 0; j < NJ; j++)
                    acc[i][j] = __builtin_amdgcn_mfma_f32_16x16x32_bf16(af[i], bfv[j], acc[i][j], 0, 0, 0);
        }
        __syncthreads();
    }

#pragma unroll
    for (int i = 0; i < 4; i++) {
        const int row = wm * 64 + i * 16 + quad * 4;
#pragma unroll
        for (int j = 0; j < NJ; j++) {
            const int col = wn * (TN / 2) + j * 16 + r;
            float bv = (EPI == 3) ? bias[bn * TN + col] : 0.f;
#pragma unroll
            for (int g = 0; g < 4; g++) {
                float v = acc[i][j][g] + bv;
                if (EPI == 3) v = fmaxf(v, 0.f);
                Cs[(row + g) * EPS + col] = f2bf(v);
            }
        }
    }
    __syncthreads();

    const int tpr = TN / 8;
    const int rpp = 2048 / TN;
    const int srow2 = tid / tpr;
    const int scol2 = (tid % tpr) * 8;
#pragma unroll
    for (int pp = 0; pp < TN / 16; pp++) {
        const int rr = pp * rpp + srow2;
        uint4 vv = *(const uint4*)&Cs[rr * EPS + scol2];
        *(uint4*)&dst0[(size_t)(bm * 128 + rr) * N + bn * TN + scol2] = vv;
    }
}

// ---------------- banded attention column-sum kernel ----------------
__global__ __launch_bounds__(256) void k_attn(const ush* __restrict__ qb,
                                              const ush* __restrict__ kb,
                                              const float* __restrict__ mask,
                                              float* __restrict__ wcol) {
    __shared__ ush   Qs[64][72];
    __shared__ ush   Ks[64][72];
    __shared__ float colpart[4][64];

    const int tid  = threadIdx.x;
    const int wave = tid >> 6, lane = tid & 63;
    const int quad = lane >> 4, r = lane & 15;
    const int bh = blockIdx.x, bi = bh >> 4, hi = bh & 15;
    const int q0 = blockIdx.y * 64;

    {
        int row = tid >> 2, seg = (tid & 3) * 16;
        const ush* src = qb + ((size_t)(bi * CS + q0 + row) * CD + hi * 64 + seg);
        *(uint4*)&Qs[row][seg]     = *(const uint4*)src;
        *(uint4*)&Qs[row][seg + 8] = *(const uint4*)(src + 8);
    }
    __syncthreads();
    bf16x8 af0 = *(const bf16x8*)&Qs[wave * 16 + r][quad * 8];
    bf16x8 af1 = *(const bf16x8*)&Qs[wave * 16 + r][32 + quad * 8];

    float mq[4];
#pragma unroll
    for (int g = 0; g < 4; g++) mq[g] = mask[bi * CS + q0 + wave * 16 + quad * 4 + g];

    const int t0 = (q0 >= 128) ? 0 : ((q0 >= 64) ? 1 : 2);
    float pr[3][4][4];
    float s_loc[4] = {0.f, 0.f, 0.f, 0.f};

    for (int t = t0; t < 3; t++) {
        const int l0 = q0 - 128 + t * 64;
        __syncthreads();
        {
            int row = tid >> 2, seg = (tid & 3) * 16;
            const ush* src = kb + ((size_t)(bi * CS + l0 + row) * CD + hi * 64 + seg);
            *(uint4*)&Ks[row][seg]     = *(const uint4*)src;
            *(uint4*)&Ks[row][seg + 8] = *(const uint4*)(src + 8);
        }
        __syncthreads();
#pragma unroll
        for (int jt = 0; jt < 4; jt++) {
            bf16x8 bf0 = *(const bf16x8*)&Ks[jt * 16 + r][quad * 8];
            bf16x8 bf1 = *(const bf16x8*)&Ks[jt * 16 + r][32 + quad * 8];
            f32x4 sc = (f32x4){0.f, 0.f, 0.f, 0.f};
            sc = __builtin_amdgcn_mfma_f32_16x16x32_bf16(af0, bf0, sc, 0, 0, 0);
            sc = __builtin_amdgcn_mfma_f32_16x16x32_bf16(af1, bf1, sc, 0, 0, 0);
            const int l = l0 + jt * 16 + r;
            const float ml = mask[bi * CS + l];
#pragma unroll
            for (int g = 0; g < 4; g++) {
                const int qg = q0 + wave * 16 + quad * 4 + g;
                float e  = sc[g] * 0.03125f;
                float mv = (qg > l) ? 0.f : mq[g] * ml * (-1e20f);
                float p  = __expf(e + mv - fabsf((float)(qg - l)) - 8.f);
                pr[t][jt][g] = p;
                s_loc[g] += p;
            }
        }
    }

    float rs[4];
#pragma unroll
    for (int g = 0; g < 4; g++) {
        float s = s_loc[g];
        s += __shfl_xor(s, 1); s += __shfl_xor(s, 2);
        s += __shfl_xor(s, 4); s += __shfl_xor(s, 8);
        rs[g] = (s > 0.f) ? 1.f / s : 0.f;
    }

    for (int t = t0; t < 3; t++) {
        const int l0 = q0 - 128 + t * 64;
#pragma unroll
        for (int jt = 0; jt < 4; jt++) {
            float csum = 0.f;
#pragma unroll
            for (int g = 0; g < 4; g++) csum += pr[t][jt][g] * rs[g];
            csum += __shfl_xor(csum, 16);
            csum += __shfl_xor(csum, 32);
            if (quad == 0) colpart[wave][jt * 16 + r] = csum;
        }
        __syncthreads();
        if (tid < 64) {
            float v = colpart[0][tid] + colpart[1][tid] + colpart[2][tid] + colpart[3][tid];
            atomicAdd(&wcol[(size_t)bh * CS + l0 + tid], v);
        }
        __syncthreads();
    }
}

// ---------------- scale v by column weights ----------------
__global__ __launch_bounds__(256) void k_scale_v(const ush* __restrict__ vb,
                                                 const float* __restrict__ wcol,
                                                 ush* __restrict__ out) {
    const int g = blockIdx.x * 256 + threadIdx.x;
    const int token = g >> 7;
    const int cg = g & 127;
    const int c0 = cg * 8, h = cg >> 3;
    const int l = token & (CS - 1), b = token >> 10;
    const float w = wcol[(size_t)(b * CH + h) * CS + l] + (1.f / 1024.f);
    float d[8];
    ub8(*(const uint4*)&vb[(size_t)token * CD + c0], d);
#pragma unroll
    for (int j = 0; j < 8; j++) d[j] *= w;
    *(uint4*)&out[(size_t)token * CD + c0] = pb8(d);
}

// ---------------- row layernorm over D=1024, fused variants ----------------
// MODE 0: LN(b0+b1+badd) -> bf16                  (Wo partials + bo)
// MODE 2: sf=LN(b0); hf=LN(b1+b2); f=sigmoid(sf+hf+badd); LN(f*sf+(1-f)*hf) -> bf16
// MODE 3: LN(4 partial slices (b0,b0+SZE,b1,b1+SZE) + b2 + badd) -> f32
__device__ __forceinline__ void stats128(float s, float q, float* red,
                                         int wave, int lane, float& mu, float& rstd) {
#pragma unroll
    for (int off = 32; off >= 1; off >>= 1) {
        s += __shfl_xor(s, off);
        q += __shfl_xor(q, off);
    }
    if (lane == 0) { red[wave] = s; red[2 + wave] = q; }
    __syncthreads();
    s = red[0] + red[1];
    q = red[2] + red[3];
    mu = s * (1.f / 1024.f);
    rstd = rsqrtf(q * (1.f / 1024.f) - mu * mu + 1e-5f);
    __syncthreads();
}

template <int MODE>
__global__ __launch_bounds__(128) void k_ln_row(const ush* __restrict__ b0,
                                                const ush* __restrict__ b1,
                                                const ush* __restrict__ b2,
                                                const float* __restrict__ badd,
                                                const float* __restrict__ gam,
                                                const float* __restrict__ bet,
                                                float* __restrict__ outf,
                                                ush* __restrict__ outb) {
    __shared__ float red[4];
    const int tid = threadIdx.x, wave = tid >> 6, lane = tid & 63;
    const size_t base = (size_t)blockIdx.x * CD;
    const int c0 = tid * 8;
    float t[8], sr[8], tmp[8], gv[8], bv[8];
    float s = 0.f, q = 0.f, mu, rstd;

    *(float4*)&gv[0] = *(const float4*)&gam[c0];
    *(float4*)&gv[4] = *(const float4*)&gam[c0 + 4];
    *(float4*)&bv[0] = *(const float4*)&bet[c0];
    *(float4*)&bv[4] = *(const float4*)&bet[c0 + 4];

    if (MODE == 2) {
        float av[8];
        *(float4*)&av[0] = *(const float4*)&badd[c0];
        *(float4*)&av[4] = *(const float4*)&badd[c0 + 4];
        ub8(*(const uint4*)&b0[base + c0], sr);
        ub8(*(const uint4*)&b1[base + c0], t);
        ub8(*(const uint4*)&b2[base + c0], tmp);
#pragma unroll
        for (int j = 0; j < 8; j++) t[j] += tmp[j];
#pragma unroll
        for (int j = 0; j < 8; j++) { s += sr[j]; q += sr[j] * sr[j]; }
        stats128(s, q, red, wave, lane, mu, rstd);
#pragma unroll
        for (int j = 0; j < 8; j++) sr[j] = (sr[j] - mu) * rstd * gv[j] + bv[j];
        s = 0.f; q = 0.f;
#pragma unroll
        for (int j = 0; j < 8; j++) { s += t[j]; q += t[j] * t[j]; }
        stats128(s, q, red, wave, lane, mu, rstd);
#pragma unroll
        for (int j = 0; j < 8; j++) {
            float hf = (t[j] - mu) * rstd * gv[j] + bv[j];
            float f  = 1.f / (1.f + __expf(-(sr[j] + hf + av[j])));
            t[j] = f * sr[j] + (1.f - f) * hf;
        }
    } else if (MODE == 3) {
        float av[8];
        *(float4*)&av[0] = *(const float4*)&badd[c0];
        *(float4*)&av[4] = *(const float4*)&badd[c0 + 4];
        ub8(*(const uint4*)&b0[base + c0], t);
#pragma unroll
        for (int j = 0; j < 8; j++) t[j] += av[j];
        ub8(*(const uint4*)&b0[base + SZE + c0], tmp);
#pragma unroll
        for (int j = 0; j < 8; j++) t[j] += tmp[j];
        ub8(*(const uint4*)&b1[base + c0], tmp);
#pragma unroll
        for (int j = 0; j < 8; j++) t[j] += tmp[j];
        ub8(*(const uint4*)&b1[base + SZE + c0], tmp);
#pragma unroll
        for (int j = 0; j < 8; j++) t[j] += tmp[j];
        ub8(*(const uint4*)&b2[base + c0], tmp);
#pragma unroll
        for (int j = 0; j < 8; j++) t[j] += tmp[j];
    } else {
        float av[8];
        *(float4*)&av[0] = *(const float4*)&badd[c0];
        *(float4*)&av[4] = *(const float4*)&badd[c0 + 4];
        ub8(*(const uint4*)&b0[base + c0], t);
        ub8(*(const uint4*)&b1[base + c0], tmp);
#pragma unroll
        for (int j = 0; j < 8; j++) t[j] += tmp[j] + av[j];
    }

    s = 0.f; q = 0.f;
#pragma unroll
    for (int j = 0; j < 8; j++) { s += t[j]; q += t[j] * t[j]; }
    stats128(s, q, red, wave, lane, mu, rstd);

    float y[8];
#pragma unroll
    for (int j = 0; j < 8; j++) y[j] = (t[j] - mu) * rstd * gv[j] + bv[j];
    if (MODE == 3) {
        *(float4*)&outf[base + c0]     = *(float4*)&y[0];
        *(float4*)&outf[base + c0 + 4] = *(float4*)&y[4];
    } else {
        *(uint4*)&outb[base + c0] = pb8(y);
    }
}

// ---------------- host launch ----------------
extern "C" void kernel_launch(void* const* d_in, const int* in_sizes, int n_in,
                              void* d_out, int out_size, void* d_ws, size_t ws_size,
                              hipStream_t stream) {
    const float* x    = (const float*)d_in[0];
    const float* mask = (const float*)d_in[1];
    const float* Wq   = (const float*)d_in[2];
    const float* Wk   = (const float*)d_in[3];
    const float* Wv   = (const float*)d_in[4];
    const float* ln1g = (const float*)d_in[5];
    const float* ln1b = (const float*)d_in[6];
    const float* Wo   = (const float*)d_in[7];
    const float* bo   = (const float*)d_in[8];
    const float* ln2g = (const float*)d_in[9];
    const float* ln2b = (const float*)d_in[10];
    const float* Ws   = (const float*)d_in[11];
    const float* Wh   = (const float*)d_in[12];
    const float* bf_  = (const float*)d_in[13];
    const float* lnfgg = (const float*)d_in[14];
    const float* lnfgb = (const float*)d_in[15];
    const float* Wp1  = (const float*)d_in[16];
    const float* bp1  = (const float*)d_in[17];
    const float* Wp2  = (const float*)d_in[18];
    const float* bp2  = (const float*)d_in[19];
    const float* lnffg = (const float*)d_in[20];
    const float* lnffb = (const float*)d_in[21];
    float* out = (float*)d_out;

    char* p = (char*)d_ws;
    auto alloc = [&](size_t bytes) -> char* {
        char* r = p;
        p += (bytes + 255) & ~(size_t)255;
        return r;
    };
    ush*   arena = (ush*)alloc((size_t)14 * CD * CD * 2);  // 28 MB
    ush*   Wob   = arena + (size_t)4 * CD * CD;
    ush*   Whb   = arena + (size_t)5 * CD * CD;
    ush*   Wp1b  = arena + (size_t)6 * CD * CD;
    ush*   Wp2b  = arena + (size_t)10 * CD * CD;
    ush*   xb    = (ush*)alloc((size_t)CNT * CD * 2);      // 8 MB
    ush*   klnb  = (ush*)alloc((size_t)CNT * CD * 2);      // 8 MB (hb alias)
    ush*   vb    = (ush*)alloc((size_t)CNT * CD * 2);      // 8 MB
    ush*   qlnb  = (ush*)alloc((size_t)CNT * CD * 2);      // 8 MB (attb alias)
    ush*   gb    = (ush*)alloc((size_t)CNT * CD * 2);      // 8 MB
    ush*   P     = (ush*)alloc((size_t)2 * CNT * CD * 2);  // 16 MB split-K bf16 partials
    ush*   P1    = P + SZE;
    ush*   ff1b  = (ush*)alloc((size_t)CNT * CDFF * 2);    // 32 MB (sbuf aliases front)
    float* wcol  = (float*)alloc((size_t)CB * CH * CS * 4);
    ush*   sbuf  = ff1b;           // s raw bf16; consumed by gate LN before FFN1 writes
    ush*   attb  = qlnb;           // q-ln consumed by k_attn before k_scale_v writes
    ush*   hb    = klnb;           // k-ln consumed by k_attn before ln_row<0> writes
    ush*   P23   = arena;          // FFN2 split-K slices 2,3 over dead Wq..Ws region

    dim3 blk(256);
    dim3 gblk(512);

    k_convert_all<<<dim3(4608), blk, 0, stream>>>(
        (const float4*)Wq, (const float4*)Wk, (const float4*)Wv, (const float4*)Ws,
        (const float4*)Wo, (const float4*)Wh, (const float4*)Wp1, (const float4*)Wp2,
        (const float4*)x, (uint4*)arena, (uint4*)xb, (float4*)wcol);

    // fused QKVS projection (8-phase 256^2): q,k,v per-head-LN -> bf16; s raw -> bf16
    k_gemm8<4, 1><<<dim3(16, 16, 1), gblk, 0, stream>>>(
        xb, arena, qlnb, ln1g, ln1b, klnb, vb, sbuf, 4096, CD);

    // attention column sums (banded)
    k_attn<<<dim3(CB * CH, CS / 64), blk, 0, stream>>>(qlnb, klnb, mask, wcol);
    k_scale_v<<<dim3(CNT * CD / 8 / 256), blk, 0, stream>>>(vb, wcol, attb);

    // output projection (split-K=2 bf16 partials) + LN2 (+bo)
    k_gemm_bt<64, 0, 2><<<dim3(32, 16, 2), blk, 0, stream>>>(
        attb, Wob, P, nullptr, nullptr, nullptr, nullptr, nullptr, CD, CD);
    k_ln_row<0><<<dim3(CNT), dim3(128), 0, stream>>>(P, P1, nullptr, bo, ln2g, ln2b, nullptr, hb);

    // h_f path + gate (s_f LN fused here)
    k_gemm_bt<64, 0, 2><<<dim3(32, 16, 2), blk, 0, stream>>>(
        hb, Whb, P, nullptr, nullptr, nullptr, nullptr, nullptr, CD, CD);
    k_ln_row<2><<<dim3(CNT), dim3(128), 0, stream>>>(sbuf, P, P1, bf_, lnfgg, lnfgb, nullptr, gb);

    // FFN1 (8-phase, +bias relu)
    k_gemm8<3, 1><<<dim3(16, 16, 1), gblk, 0, stream>>>(
        gb, Wp1b, ff1b, bp1, nullptr, nullptr, nullptr, nullptr, CDFF, CD);
    // FFN2 (8-phase, split-K=4: slices 0,1 -> P; 2,3 -> arena) + final LN (+g+bp2)
    k_gemm8<0, 4><<<dim3(16, 4, 4), gblk, 0, stream>>>(
        ff1b, Wp2b, P, nullptr, nullptr, P23, nullptr, nullptr, CD, CDFF);
    k_ln_row<3><<<dim3(CNT), dim3(128), 0, stream>>>(P, P23, gb, bp2, lnffg, lnffb, out, nullptr);

    (void)in_sizes; (void)n_in; (void)out_size; (void)ws_size;
}

// Round 5
// 328.144 us; speedup vs baseline: 1.1161x; 1.1161x over previous
//
#include <hip/hip_runtime.h>

// ---------------- problem constants ----------------
constexpr int CB   = 4;
constexpr int CS   = 1024;
constexpr int CD   = 1024;
constexpr int CH   = 16;
constexpr int CDFF = 4096;
constexpr int CNT  = CB * CS;   // 4096 tokens

typedef unsigned short ush;
typedef __bf16 bf16_t;
typedef bf16_t bf16x8 __attribute__((ext_vector_type(8)));
typedef float  f32x4  __attribute__((ext_vector_type(4)));

__device__ __forceinline__ ush f2bf(float f) {
    union { float f; unsigned u; } v; v.f = f;
    unsigned u = v.u;
    return (ush)((u + 0x7fffu + ((u >> 16) & 1u)) >> 16);
}
__device__ __forceinline__ float bf2f(ush h) {
    union { unsigned u; float f; } v; v.u = ((unsigned)h) << 16;
    return v.f;
}
__device__ __forceinline__ void ub8(uint4 v, float* d) {
    d[0] = bf2f((ush)v.x); d[1] = bf2f((ush)(v.x >> 16));
    d[2] = bf2f((ush)v.y); d[3] = bf2f((ush)(v.y >> 16));
    d[4] = bf2f((ush)v.z); d[5] = bf2f((ush)(v.z >> 16));
    d[6] = bf2f((ush)v.w); d[7] = bf2f((ush)(v.w >> 16));
}
__device__ __forceinline__ uint4 pb8(const float* d) {
    uint4 v;
    v.x = (unsigned)f2bf(d[0]) | ((unsigned)f2bf(d[1]) << 16);
    v.y = (unsigned)f2bf(d[2]) | ((unsigned)f2bf(d[3]) << 16);
    v.z = (unsigned)f2bf(d[4]) | ((unsigned)f2bf(d[5]) << 16);
    v.w = (unsigned)f2bf(d[6]) | ((unsigned)f2bf(d[7]) << 16);
    return v;
}

// async global->LDS, 16B per lane (dest = wave-uniform base + lane*16)
__device__ __forceinline__ void gll16(const void* g, void* l) {
    __builtin_amdgcn_global_load_lds((const __attribute__((address_space(1))) void*)g,
                                     (__attribute__((address_space(3))) void*)l,
                                     16, 0, 0);
}

// ---------------- fused conversions (x + all weights) + wcol zero ----------------
// arena (elements): [Wq 1M | Wk 1M | Wv 1M | Ws 1M | Wo 1M | Wh 1M | Wp1 4M | Wp2 4M]
constexpr int Q4 = (CD * CD) / 4;   // 2^18 float4 per 1M-elem matrix
__global__ __launch_bounds__(256) void k_convert_all(
        const float4* __restrict__ Wq, const float4* __restrict__ Wk,
        const float4* __restrict__ Wv, const float4* __restrict__ Ws,
        const float4* __restrict__ Wo, const float4* __restrict__ Wh,
        const float4* __restrict__ Wp1, const float4* __restrict__ Wp2,
        const float4* __restrict__ x, uint4* __restrict__ arena,
        uint4* __restrict__ xb, float4* __restrict__ wz) {
    int i = blockIdx.x * 256 + threadIdx.x;
    int stride = gridDim.x * 256;
    for (int i2 = i; i2 < (CB * CH * CS) / 4; i2 += stride)
        wz[i2] = (float4){0.f, 0.f, 0.f, 0.f};
    for (; i < 9 * Q4; i += stride) {
        const int F = i * 2;               // float4 index
        const int seg = F >> 18;           // Q4 = 2^18
        const float4* src; int off;
        if (seg < 6) {
            src = (seg == 0) ? Wq : (seg == 1) ? Wk : (seg == 2) ? Wv
                : (seg == 3) ? Ws : (seg == 4) ? Wo : Wh;
            off = F & (Q4 - 1);
        } else if (seg < 10) { src = Wp1; off = F - 6 * Q4; }
        else if (seg < 14)   { src = Wp2; off = F - 10 * Q4; }
        else                 { src = x;   off = F - 14 * Q4; }
        float4 a = src[off], b = src[off + 1];
        uint4 o;
        o.x = (unsigned)f2bf(a.x) | ((unsigned)f2bf(a.y) << 16);
        o.y = (unsigned)f2bf(a.z) | ((unsigned)f2bf(a.w) << 16);
        o.z = (unsigned)f2bf(b.x) | ((unsigned)f2bf(b.y) << 16);
        o.w = (unsigned)f2bf(b.z) | ((unsigned)f2bf(b.w) << 16);
        if (seg < 14) arena[i] = o;
        else          xb[i - 7 * Q4] = o;
    }
}

// ---------------- bf16 MFMA GEMM: C[M,N] = A[M,K]*B[N,K]^T ----------------
// BK=64, XOR-swizzled LDS staging (conflict-free gll16 writes AND b128 frag reads).
// Epilogue: LDS-staged transpose -> full-line global_store_dwordx4.
// EPI 0: bf16 partial out (split-K slices stacked at z*M*N, summed in LN).
// EPI 3: +bias relu bf16 out. EPI 4: QKVS fused per-head-LN epilogue.
template <int TN, int EPI, int SPLITK>
__global__ __launch_bounds__(256, 4) void k_gemm_bt(
        const ush* __restrict__ A, const ush* __restrict__ Bm,
        ush* __restrict__ Cb,
        const float* __restrict__ bias, const float* __restrict__ bias2,
        ush* __restrict__ out2, ush* __restrict__ out3, ush* __restrict__ sb,
        int N, int K) {
    constexpr int NJ  = TN / 32;
    constexpr int BCH = TN / 32;
    constexpr int EPS = TN + 8;
    constexpr int STG = (128 + TN) * 64;
    constexpr int LDS_USH = (STG > 128 * EPS) ? STG : 128 * EPS;
    __shared__ ush smem[LDS_USH];
    ush* As = smem;
    ush* Bs = smem + 128 * 64;
    ush* Cs = smem;

    const int tid  = threadIdx.x;
    const int wave = tid >> 6, lane = tid & 63;
    const int quad = lane >> 4, r = lane & 15;
    const int wm = wave >> 1, wn = wave & 1;
    const int bm = blockIdx.x, bn = blockIdx.y;

    const int kcnt  = K / SPLITK;
    const int kbase = blockIdx.z * kcnt;
    ush* dst0 = Cb;
    if (SPLITK > 1) dst0 += (size_t)blockIdx.z * (size_t)gridDim.x * 128 * N;

    const int trow = tid >> 3, tk8 = tid & 7;
    const int kcl  = tk8 ^ (trow & 7);
    const ush* ap = A  + (size_t)(bm * 128 + trow) * K + kbase + kcl * 8;
    const ush* bp = Bm + (size_t)(bn * TN  + trow) * K + kbase + kcl * 8;
    ush* asd = As + tid * 8;
    ush* bsd = Bs + tid * 8;
    const size_t cstep = (size_t)32 * K;

    f32x4 acc[4][NJ];
#pragma unroll
    for (int i = 0; i < 4; i++)
#pragma unroll
        for (int j = 0; j < NJ; j++) acc[i][j] = (f32x4){0.f, 0.f, 0.f, 0.f};

    const int rx = r & 7;
    for (int k0 = 0; k0 < kcnt; k0 += 64) {
#pragma unroll
        for (int c = 0; c < 4; c++)   gll16(ap + c * cstep, asd + c * 2048);
#pragma unroll
        for (int c = 0; c < BCH; c++) gll16(bp + c * cstep, bsd + c * 2048);
        ap += 64; bp += 64;
        __syncthreads();
#pragma unroll
        for (int h = 0; h < 2; h++) {
            const int kx = (((h << 2) | quad) ^ rx) * 8;
            bf16x8 af[4], bfv[NJ];
#pragma unroll
            for (int i = 0; i < 4; i++)
                af[i] = *(const bf16x8*)(As + (wm * 64 + i * 16 + r) * 64 + kx);
#pragma unroll
            for (int j = 0; j < NJ; j++)
                bfv[j] = *(const bf16x8*)(Bs + (wn * (TN / 2) + j * 16 + r) * 64 + kx);
#pragma unroll
            for (int i = 0; i < 4; i++)
#pragma unroll
                for (int j = 0; j < NJ; j++)
                    acc[i][j] = __builtin_amdgcn_mfma_f32_16x16x32_bf16(af[i], bfv[j], acc[i][j], 0, 0, 0);
        }
        __syncthreads();
    }

    // ---- deposit output tile into LDS (bf16, padded rows) ----
    if (EPI == 4 && bn < 24) {
        float g4[4], b4[4];
#pragma unroll
        for (int j = 0; j < 4; j++) { g4[j] = bias[j * 16 + r]; b4[j] = bias2[j * 16 + r]; }
#pragma unroll
        for (int i = 0; i < 4; i++) {
            const int row = wm * 64 + i * 16 + quad * 4;
#pragma unroll
            for (int g = 0; g < 4; g++) {
                float s = 0.f, q = 0.f;
#pragma unroll
                for (int j = 0; j < 4; j++) { float v = acc[i][j][g]; s += v; q += v * v; }
                s += __shfl_xor(s, 1); q += __shfl_xor(q, 1);
                s += __shfl_xor(s, 2); q += __shfl_xor(q, 2);
                s += __shfl_xor(s, 4); q += __shfl_xor(q, 4);
                s += __shfl_xor(s, 8); q += __shfl_xor(q, 8);
                float mu   = s * (1.f / 64.f);
                float rstd = rsqrtf(q * (1.f / 64.f) - mu * mu + 1e-5f);
#pragma unroll
                for (int j = 0; j < 4; j++) {
                    float y = (acc[i][j][g] - mu) * rstd * g4[j] + b4[j];
                    Cs[(row + g) * EPS + wn * 64 + j * 16 + r] = f2bf(y);
                }
            }
        }
    } else {
#pragma unroll
        for (int i = 0; i < 4; i++) {
            const int row = wm * 64 + i * 16 + quad * 4;
#pragma unroll
            for (int j = 0; j < NJ; j++) {
                const int col = wn * (TN / 2) + j * 16 + r;
                float bv = (EPI == 3) ? bias[bn * TN + col] : 0.f;
#pragma unroll
                for (int g = 0; g < 4; g++) {
                    float v = acc[i][j][g] + bv;
                    if (EPI == 3) v = fmaxf(v, 0.f);
                    Cs[(row + g) * EPS + col] = f2bf(v);
                }
            }
        }
    }
    __syncthreads();

    // ---- vectorized store: full 128B-line coverage ----
    ush* dst = dst0;
    int colbase = bn * TN, Nn = N;
    if (EPI == 4) {
        Nn = 1024;
        if (bn < 8)       { dst = Cb;   colbase = bn * 128; }
        else if (bn < 16) { dst = out2; colbase = (bn - 8) * 128; }
        else if (bn < 24) { dst = out3; colbase = (bn - 16) * 128; }
        else              { dst = sb;   colbase = (bn - 24) * 128; }
    }
    const int tpr = TN / 8;
    const int rpp = 2048 / TN;
    const int srow2 = tid / tpr;
    const int scol2 = (tid % tpr) * 8;
#pragma unroll
    for (int pp = 0; pp < TN / 16; pp++) {
        const int rr = pp * rpp + srow2;
        uint4 vv = *(const uint4*)&Cs[rr * EPS + scol2];
        *(uint4*)&dst[(size_t)(bm * 128 + rr) * Nn + colbase + scol2] = vv;
    }
}

// ---------------- banded attention column-sum kernel ----------------
// wcol[b,h,l] = sum_q softmax_row_q(pre)[l]; exp(pre-8)==0 in fp32 for |q-l|>~104,
// so 3 K-tiles of 64 suffice. All-masked row q=0 adds uniform 1/1024 in k_scale_v.
// NOTE: t-loops are statically unrolled (0..2) with a block-uniform l0>=0 guard so
// pr[] stays in registers (runtime t0 start => dynamic indexing => scratch, rule #20).
__global__ __launch_bounds__(256) void k_attn(const ush* __restrict__ qb,
                                              const ush* __restrict__ kb,
                                              const float* __restrict__ mask,
                                              float* __restrict__ wcol) {
    __shared__ ush   Qs[64][72];
    __shared__ ush   Ks[64][72];
    __shared__ float colpart[4][64];

    const int tid  = threadIdx.x;
    const int wave = tid >> 6, lane = tid & 63;
    const int quad = lane >> 4, r = lane & 15;
    const int bh = blockIdx.x, bi = bh >> 4, hi = bh & 15;
    const int q0 = blockIdx.y * 64;

    {
        int row = tid >> 2, seg = (tid & 3) * 16;
        const ush* src = qb + ((size_t)(bi * CS + q0 + row) * CD + hi * 64 + seg);
        *(uint4*)&Qs[row][seg]     = *(const uint4*)src;
        *(uint4*)&Qs[row][seg + 8] = *(const uint4*)(src + 8);
    }
    __syncthreads();
    bf16x8 af0 = *(const bf16x8*)&Qs[wave * 16 + r][quad * 8];
    bf16x8 af1 = *(const bf16x8*)&Qs[wave * 16 + r][32 + quad * 8];

    float mq[4];
#pragma unroll
    for (int g = 0; g < 4; g++) mq[g] = mask[bi * CS + q0 + wave * 16 + quad * 4 + g];

    float pr[3][4][4];
    float s_loc[4] = {0.f, 0.f, 0.f, 0.f};

#pragma unroll
    for (int t = 0; t < 3; t++) {
        const int l0 = q0 - 128 + t * 64;
        if (l0 >= 0) {                       // block-uniform (q0 uniform)
            __syncthreads();
            {
                int row = tid >> 2, seg = (tid & 3) * 16;
                const ush* src = kb + ((size_t)(bi * CS + l0 + row) * CD + hi * 64 + seg);
                *(uint4*)&Ks[row][seg]     = *(const uint4*)src;
                *(uint4*)&Ks[row][seg + 8] = *(const uint4*)(src + 8);
            }
            __syncthreads();
#pragma unroll
            for (int jt = 0; jt < 4; jt++) {
                bf16x8 bf0 = *(const bf16x8*)&Ks[jt * 16 + r][quad * 8];
                bf16x8 bf1 = *(const bf16x8*)&Ks[jt * 16 + r][32 + quad * 8];
                f32x4 sc = (f32x4){0.f, 0.f, 0.f, 0.f};
                sc = __builtin_amdgcn_mfma_f32_16x16x32_bf16(af0, bf0, sc, 0, 0, 0);
                sc = __builtin_amdgcn_mfma_f32_16x16x32_bf16(af1, bf1, sc, 0, 0, 0);
                const int l = l0 + jt * 16 + r;
                const float ml = mask[bi * CS + l];
#pragma unroll
                for (int g = 0; g < 4; g++) {
                    const int qg = q0 + wave * 16 + quad * 4 + g;
                    float e  = sc[g] * 0.03125f;
                    float mv = (qg > l) ? 0.f : mq[g] * ml * (-1e20f);
                    float p  = __expf(e + mv - fabsf((float)(qg - l)) - 8.f);
                    pr[t][jt][g] = p;
                    s_loc[g] += p;
                }
            }
        }
    }

    float rs[4];
#pragma unroll
    for (int g = 0; g < 4; g++) {
        float s = s_loc[g];
        s += __shfl_xor(s, 1); s += __shfl_xor(s, 2);
        s += __shfl_xor(s, 4); s += __shfl_xor(s, 8);
        rs[g] = (s > 0.f) ? 1.f / s : 0.f;
    }

#pragma unroll
    for (int t = 0; t < 3; t++) {
        const int l0 = q0 - 128 + t * 64;
        if (l0 >= 0) {                       // block-uniform
#pragma unroll
            for (int jt = 0; jt < 4; jt++) {
                float csum = 0.f;
#pragma unroll
                for (int g = 0; g < 4; g++) csum += pr[t][jt][g] * rs[g];
                csum += __shfl_xor(csum, 16);
                csum += __shfl_xor(csum, 32);
                if (quad == 0) colpart[wave][jt * 16 + r] = csum;
            }
            __syncthreads();
            if (tid < 64) {
                float v = colpart[0][tid] + colpart[1][tid] + colpart[2][tid] + colpart[3][tid];
                atomicAdd(&wcol[(size_t)bh * CS + l0 + tid], v);
            }
            __syncthreads();
        }
    }
}

// ---------------- scale v by column weights (+ uniform row-0 term), 8 elems/thread ----
__global__ __launch_bounds__(256) void k_scale_v(const ush* __restrict__ vb,
                                                 const float* __restrict__ wcol,
                                                 ush* __restrict__ out) {
    const int g = blockIdx.x * 256 + threadIdx.x;   // group of 8 elems
    const int token = g >> 7;
    const int cg = g & 127;
    const int c0 = cg * 8, h = cg >> 3;
    const int l = token & (CS - 1), b = token >> 10;
    const float w = wcol[(size_t)(b * CH + h) * CS + l] + (1.f / 1024.f);
    float d[8];
    ub8(*(const uint4*)&vb[(size_t)token * CD + c0], d);
#pragma unroll
    for (int j = 0; j < 8; j++) d[j] *= w;
    *(uint4*)&out[(size_t)token * CD + c0] = pb8(d);
}

// ---------------- row layernorm over D=1024 (bf16 in, 16B/lane), fused variants ----
// MODE 0: LN(b0+b1+badd) -> bf16                        (Wo partials + bo)
// MODE 2: sf=LN(b0); hf=LN(b1+b2); f=sigmoid(sf+hf+badd); LN(f*sf+(1-f)*hf) -> bf16
// MODE 3: LN(b0+b1+b2+badd) -> f32                      (FFN2 partials + g + bp2)
__device__ __forceinline__ void stats128(float s, float q, float* red,
                                         int wave, int lane, float& mu, float& rstd) {
#pragma unroll
    for (int off = 32; off >= 1; off >>= 1) {
        s += __shfl_xor(s, off);
        q += __shfl_xor(q, off);
    }
    if (lane == 0) { red[wave] = s; red[2 + wave] = q; }
    __syncthreads();
    s = red[0] + red[1];
    q = red[2] + red[3];
    mu = s * (1.f / 1024.f);
    rstd = rsqrtf(q * (1.f / 1024.f) - mu * mu + 1e-5f);
    __syncthreads();
}

template <int MODE>
__global__ __launch_bounds__(128) void k_ln_row(const ush* __restrict__ b0,
                                                const ush* __restrict__ b1,
                                                const ush* __restrict__ b2,
                                                const float* __restrict__ badd,
                                                const float* __restrict__ gam,
                                                const float* __restrict__ bet,
                                                float* __restrict__ outf,
                                                ush* __restrict__ outb) {
    __shared__ float red[4];
    const int tid = threadIdx.x, wave = tid >> 6, lane = tid & 63;
    const size_t base = (size_t)blockIdx.x * CD;
    const int c0 = tid * 8;
    float t[8], sr[8], tmp[8], gv[8], bv[8];
    float s = 0.f, q = 0.f, mu, rstd;

    *(float4*)&gv[0] = *(const float4*)&gam[c0];
    *(float4*)&gv[4] = *(const float4*)&gam[c0 + 4];
    *(float4*)&bv[0] = *(const float4*)&bet[c0];
    *(float4*)&bv[4] = *(const float4*)&bet[c0 + 4];

    if (MODE == 2) {
        float av[8];
        *(float4*)&av[0] = *(const float4*)&badd[c0];
        *(float4*)&av[4] = *(const float4*)&badd[c0 + 4];
        ub8(*(const uint4*)&b0[base + c0], sr);
        ub8(*(const uint4*)&b1[base + c0], t);
        ub8(*(const uint4*)&b2[base + c0], tmp);
#pragma unroll
        for (int j = 0; j < 8; j++) t[j] += tmp[j];
#pragma unroll
        for (int j = 0; j < 8; j++) { s += sr[j]; q += sr[j] * sr[j]; }
        stats128(s, q, red, wave, lane, mu, rstd);
#pragma unroll
        for (int j = 0; j < 8; j++) sr[j] = (sr[j] - mu) * rstd * gv[j] + bv[j];  // s_f
        s = 0.f; q = 0.f;
#pragma unroll
        for (int j = 0; j < 8; j++) { s += t[j]; q += t[j] * t[j]; }
        stats128(s, q, red, wave, lane, mu, rstd);
#pragma unroll
        for (int j = 0; j < 8; j++) {
            float hf = (t[j] - mu) * rstd * gv[j] + bv[j];
            float f  = 1.f / (1.f + __expf(-(sr[j] + hf + av[j])));
            t[j] = f * sr[j] + (1.f - f) * hf;
        }
    } else {
        float av[8];
        *(float4*)&av[0] = *(const float4*)&badd[c0];
        *(float4*)&av[4] = *(const float4*)&badd[c0 + 4];
        ub8(*(const uint4*)&b0[base + c0], t);
        ub8(*(const uint4*)&b1[base + c0], tmp);
#pragma unroll
        for (int j = 0; j < 8; j++) t[j] += tmp[j] + av[j];
        if (MODE == 3) {
            ub8(*(const uint4*)&b2[base + c0], tmp);
#pragma unroll
            for (int j = 0; j < 8; j++) t[j] += tmp[j];
        }
    }

    s = 0.f; q = 0.f;
#pragma unroll
    for (int j = 0; j < 8; j++) { s += t[j]; q += t[j] * t[j]; }
    stats128(s, q, red, wave, lane, mu, rstd);

    float y[8];
#pragma unroll
    for (int j = 0; j < 8; j++) y[j] = (t[j] - mu) * rstd * gv[j] + bv[j];
    if (MODE == 3) {
        *(float4*)&outf[base + c0]     = *(float4*)&y[0];
        *(float4*)&outf[base + c0 + 4] = *(float4*)&y[4];
    } else {
        *(uint4*)&outb[base + c0] = pb8(y);
    }
}

// ---------------- host launch ----------------
extern "C" void kernel_launch(void* const* d_in, const int* in_sizes, int n_in,
                              void* d_out, int out_size, void* d_ws, size_t ws_size,
                              hipStream_t stream) {
    const float* x    = (const float*)d_in[0];
    const float* mask = (const float*)d_in[1];
    const float* Wq   = (const float*)d_in[2];
    const float* Wk   = (const float*)d_in[3];
    const float* Wv   = (const float*)d_in[4];
    const float* ln1g = (const float*)d_in[5];
    const float* ln1b = (const float*)d_in[6];
    const float* Wo   = (const float*)d_in[7];
    const float* bo   = (const float*)d_in[8];
    const float* ln2g = (const float*)d_in[9];
    const float* ln2b = (const float*)d_in[10];
    const float* Ws   = (const float*)d_in[11];
    const float* Wh   = (const float*)d_in[12];
    const float* bf_  = (const float*)d_in[13];
    const float* lnfgg = (const float*)d_in[14];
    const float* lnfgb = (const float*)d_in[15];
    const float* Wp1  = (const float*)d_in[16];
    const float* bp1  = (const float*)d_in[17];
    const float* Wp2  = (const float*)d_in[18];
    const float* bp2  = (const float*)d_in[19];
    const float* lnffg = (const float*)d_in[20];
    const float* lnffb = (const float*)d_in[21];
    float* out = (float*)d_out;

    char* p = (char*)d_ws;
    auto alloc = [&](size_t bytes) -> char* {
        char* r = p;
        p += (bytes + 255) & ~(size_t)255;
        return r;
    };
    ush*   arena = (ush*)alloc((size_t)14 * CD * CD * 2);  // 28 MB
    ush*   Wob   = arena + (size_t)4 * CD * CD;
    ush*   Whb   = arena + (size_t)5 * CD * CD;
    ush*   Wp1b  = arena + (size_t)6 * CD * CD;
    ush*   Wp2b  = arena + (size_t)10 * CD * CD;
    ush*   xb    = (ush*)alloc((size_t)CNT * CD * 2);      // 8 MB
    ush*   klnb  = (ush*)alloc((size_t)CNT * CD * 2);      // 8 MB (hb alias)
    ush*   vb    = (ush*)alloc((size_t)CNT * CD * 2);      // 8 MB
    ush*   qlnb  = (ush*)alloc((size_t)CNT * CD * 2);      // 8 MB (attb alias)
    ush*   gb    = (ush*)alloc((size_t)CNT * CD * 2);      // 8 MB
    ush*   P     = (ush*)alloc((size_t)2 * CNT * CD * 2);  // 16 MB split-K bf16 partials
    ush*   P1    = P + (size_t)CNT * CD;
    ush*   ff1b  = (ush*)alloc((size_t)CNT * CDFF * 2);    // 32 MB (sbuf aliases front)
    float* wcol  = (float*)alloc((size_t)CB * CH * CS * 4);
    ush*   sbuf  = ff1b;           // s raw bf16; consumed by gate LN before FFN1 writes
    ush*   attb  = qlnb;           // q-ln consumed by k_attn before k_scale_v writes
    ush*   hb    = klnb;           // k-ln consumed by k_attn before ln_row<0> writes

    dim3 blk(256);

    k_convert_all<<<dim3(4608), blk, 0, stream>>>(
        (const float4*)Wq, (const float4*)Wk, (const float4*)Wv, (const float4*)Ws,
        (const float4*)Wo, (const float4*)Wh, (const float4*)Wp1, (const float4*)Wp2,
        (const float4*)x, (uint4*)arena, (uint4*)xb, (float4*)wcol);

    // fused QKVS projection: q,k,v per-head-LN -> bf16; s raw -> bf16
    k_gemm_bt<128, 4, 1><<<dim3(32, 32, 1), blk, 0, stream>>>(
        xb, arena, qlnb, ln1g, ln1b, klnb, vb, sbuf, 4096, CD);

    // attention column sums (banded)
    k_attn<<<dim3(CB * CH, CS / 64), blk, 0, stream>>>(qlnb, klnb, mask, wcol);
    k_scale_v<<<dim3(CNT * CD / 8 / 256), blk, 0, stream>>>(vb, wcol, attb);

    // output projection (split-K=2 bf16 partials) + LN2 (+bo)
    k_gemm_bt<64, 0, 2><<<dim3(32, 16, 2), blk, 0, stream>>>(
        attb, Wob, P, nullptr, nullptr, nullptr, nullptr, nullptr, CD, CD);
    k_ln_row<0><<<dim3(CNT), dim3(128), 0, stream>>>(P, P1, nullptr, bo, ln2g, ln2b, nullptr, hb);

    // h_f path + gate (s_f LN fused here)
    k_gemm_bt<64, 0, 2><<<dim3(32, 16, 2), blk, 0, stream>>>(
        hb, Whb, P, nullptr, nullptr, nullptr, nullptr, nullptr, CD, CD);
    k_ln_row<2><<<dim3(CNT), dim3(128), 0, stream>>>(sbuf, P, P1, bf_, lnfgg, lnfgb, nullptr, gb);

    // FFN + residual (g as bf16) + final LN (+bp2)
    k_gemm_bt<128, 3, 1><<<dim3(32, 32, 1), blk, 0, stream>>>(
        gb, Wp1b, ff1b, bp1, nullptr, nullptr, nullptr, nullptr, CDFF, CD);
    k_gemm_bt<64, 0, 2><<<dim3(32, 16, 2), blk, 0, stream>>>(
        ff1b, Wp2b, P, nullptr, nullptr, nullptr, nullptr, nullptr, CD, CDFF);
    k_ln_row<3><<<dim3(CNT), dim3(128), 0, stream>>>(P, P1, gb, bp2, lnffg, lnffb, out, nullptr);

    (void)in_sizes; (void)n_in; (void)out_size; (void)ws_size;
}